// Round 2
// baseline (873.773 us; speedup 1.0000x reference)
//
#include <hip/hip_runtime.h>
#include <cstdint>
#include <cstddef>

#define N_PIX   16384
#define K_EMB   8192
#define DDIM    256

// ws layout (bytes)
#define WS_A        0           // A matrix, pixel-major: 16384*256*4 = 16777216
#define WS_PART     16777216    // partials: 64*16384*8 = 8388608
#define WS_ZSQ      25165824    // 16384*4 = 65536
#define WS_ESQ      25231360    // 8192*4  = 32768
#define WS_IDX      25264128    // 16384*4 = 65536
#define WS_LOSS     25329664    // 8

// ---------------------------------------------------------------- helpers
// numpy pairwise_sum over 256 contiguous fp32 squares, replicated exactly:
// n=256 -> two halves of 128; each half: 8 accumulators r[j] over elements
// j, j+8, ..., j+120 (sequential adds), combined ((r0+r1)+(r2+r3))+((r4+r5)+(r6+r7));
// total = half0 + half1. Products rounded before adding (no FMA contraction).

// ---------------------------------------------------------------- kernel 1
// zsq[p] = numpy-pairwise sum of z_p[c]^2 over c (channel axis), reading z in
// its native [B,C,H,W] layout (coalesced: lane = pixel). Also zero lossAcc.
__global__ void zsq_kernel(const float* __restrict__ z,
                           float* __restrict__ zsq,
                           double* __restrict__ lossAcc) {
    int p  = blockIdx.x * 256 + threadIdx.x;   // 0..16383
    int b  = p >> 10;
    int hw = p & 1023;
    const float* zp = z + (size_t)b * 262144 + hw;
    float r[16];
#pragma unroll
    for (int j = 0; j < 16; ++j) r[j] = 0.f;
#pragma unroll
    for (int c = 0; c < 256; ++c) {
        float x  = zp[(size_t)c * 1024];
        float sq = __fmul_rn(x, x);
        int slot = ((c >> 7) << 3) | (c & 7);
        r[slot] = __fadd_rn(r[slot], sq);
    }
    float h0 = __fadd_rn(
        __fadd_rn(__fadd_rn(r[0], r[1]), __fadd_rn(r[2], r[3])),
        __fadd_rn(__fadd_rn(r[4], r[5]), __fadd_rn(r[6], r[7])));
    float h1 = __fadd_rn(
        __fadd_rn(__fadd_rn(r[8], r[9]), __fadd_rn(r[10], r[11])),
        __fadd_rn(__fadd_rn(r[12], r[13]), __fadd_rn(r[14], r[15])));
    zsq[p] = __fadd_rn(h0, h1);
    if (p == 0) *lossAcc = 0.0;
}

// ---------------------------------------------------------------- kernel 2
// esq[k] = numpy-pairwise sum of emb_k[c]^2, one thread per codebook row.
__global__ void esq_kernel(const float* __restrict__ emb,
                           float* __restrict__ esq) {
    int k = blockIdx.x * 256 + threadIdx.x;    // 0..8191
    const float* ep = emb + (size_t)k * DDIM;
    float r[16];
#pragma unroll
    for (int j = 0; j < 16; ++j) r[j] = 0.f;
#pragma unroll
    for (int c = 0; c < 256; ++c) {
        float x  = ep[c];
        float sq = __fmul_rn(x, x);
        int slot = ((c >> 7) << 3) | (c & 7);
        r[slot] = __fadd_rn(r[slot], sq);
    }
    float h0 = __fadd_rn(
        __fadd_rn(__fadd_rn(r[0], r[1]), __fadd_rn(r[2], r[3])),
        __fadd_rn(__fadd_rn(r[4], r[5]), __fadd_rn(r[6], r[7])));
    float h1 = __fadd_rn(
        __fadd_rn(__fadd_rn(r[8], r[9]), __fadd_rn(r[10], r[11])),
        __fadd_rn(__fadd_rn(r[12], r[13]), __fadd_rn(r[14], r[15])));
    esq[k] = __fadd_rn(h0, h1);
}

// ---------------------------------------------------------------- kernel 3
// Transpose z [B,C,H,W] -> A [N_PIX][DDIM] (pixel-major), 32x32 LDS tiles.
__global__ void transpose_z_kernel(const float* __restrict__ z,
                                   float* __restrict__ A) {
    __shared__ float tile[32][33];
    int pi = blockIdx.x;  // pixel tile (p = h*32+w), 0..31
    int ci = blockIdx.y;  // channel tile, 0..7
    int b  = blockIdx.z;  // batch, 0..15
    int tx = threadIdx.x; // 0..31
    int ty = threadIdx.y; // 0..7
#pragma unroll
    for (int i = ty; i < 32; i += 8) {
        tile[i][tx] = z[((size_t)b * 256 + ci * 32 + i) * 1024 + pi * 32 + tx];
    }
    __syncthreads();
#pragma unroll
    for (int i = ty; i < 32; i += 8) {
        A[((size_t)b * 1024 + pi * 32 + i) * 256 + ci * 32 + tx] = tile[tx][i];
    }
}

// ---------------------------------------------------------------- kernel 4
// Fused fp32 GEMM + per-block argmin over the np-fp32-quantized score
//   s = round(round(zsq_p + esq_k) - 2*dot_pk)
// Block tile: 128 pixels x 128 candidates, BK=16, 256 threads, 8x8/thread.
__device__ __forceinline__ unsigned int f32_sortable(float f) {
    unsigned int u = __float_as_uint(f);
    return (u & 0x80000000u) ? ~u : (u | 0x80000000u);
}

__global__ __launch_bounds__(256) void gemm_argmin_kernel(
        const float* __restrict__ A, const float* __restrict__ E,
        const float* __restrict__ zsq, const float* __restrict__ esq,
        unsigned long long* __restrict__ partials) {
    __shared__ __align__(16) float As[16][128];
    __shared__ __align__(16) float Bs[16][128];
    __shared__ unsigned long long red[128][16];

    const int nb = blockIdx.x;   // candidate tile, 0..63
    const int mb = blockIdx.y;   // pixel tile, 0..127
    const int t  = threadIdx.x;
    const int tx = t & 15;
    const int ty = t >> 4;
    const int lr = t >> 2;        // staging row 0..63
    const int lc = (t & 3) * 4;   // staging col group

    const float* Ag = A + (size_t)mb * 128 * DDIM;
    const float* Eg = E + (size_t)nb * 128 * DDIM;

    float acc[8][8];
#pragma unroll
    for (int i = 0; i < 8; ++i)
#pragma unroll
        for (int j = 0; j < 8; ++j) acc[i][j] = 0.f;

    for (int k0 = 0; k0 < DDIM; k0 += 16) {
        float4 a0 = *(const float4*)(Ag + (size_t)lr * DDIM + k0 + lc);
        float4 a1 = *(const float4*)(Ag + (size_t)(lr + 64) * DDIM + k0 + lc);
        float4 b0 = *(const float4*)(Eg + (size_t)lr * DDIM + k0 + lc);
        float4 b1 = *(const float4*)(Eg + (size_t)(lr + 64) * DDIM + k0 + lc);
        __syncthreads();
        As[lc + 0][lr] = a0.x; As[lc + 1][lr] = a0.y;
        As[lc + 2][lr] = a0.z; As[lc + 3][lr] = a0.w;
        As[lc + 0][lr + 64] = a1.x; As[lc + 1][lr + 64] = a1.y;
        As[lc + 2][lr + 64] = a1.z; As[lc + 3][lr + 64] = a1.w;
        Bs[lc + 0][lr] = b0.x; Bs[lc + 1][lr] = b0.y;
        Bs[lc + 2][lr] = b0.z; Bs[lc + 3][lr] = b0.w;
        Bs[lc + 0][lr + 64] = b1.x; Bs[lc + 1][lr + 64] = b1.y;
        Bs[lc + 2][lr + 64] = b1.z; Bs[lc + 3][lr + 64] = b1.w;
        __syncthreads();
#pragma unroll
        for (int kk = 0; kk < 16; ++kk) {
            float4 av0 = ((const float4*)As[kk])[ty];
            float4 av1 = ((const float4*)As[kk])[16 + ty];
            float4 bv0 = ((const float4*)Bs[kk])[tx];
            float4 bv1 = ((const float4*)Bs[kk])[16 + tx];
            float a[8]  = {av0.x, av0.y, av0.z, av0.w, av1.x, av1.y, av1.z, av1.w};
            float bb[8] = {bv0.x, bv0.y, bv0.z, bv0.w, bv1.x, bv1.y, bv1.z, bv1.w};
#pragma unroll
            for (int i = 0; i < 8; ++i)
#pragma unroll
                for (int j = 0; j < 8; ++j) acc[i][j] += a[i] * bb[j];
        }
    }

    // epilogue: np-fp32 quantized score + per-block argmin over 128 candidates
    float es[8], zs[8];
#pragma unroll
    for (int j = 0; j < 8; ++j) {
        int nloc = (j < 4) ? (tx * 4 + j) : (64 + tx * 4 + (j - 4));
        es[j] = esq[nb * 128 + nloc];
    }
#pragma unroll
    for (int i = 0; i < 8; ++i) {
        int mloc = (i < 4) ? (ty * 4 + i) : (64 + ty * 4 + (i - 4));
        zs[i] = zsq[mb * 128 + mloc];
    }
#pragma unroll
    for (int i = 0; i < 8; ++i) {
        int mloc = (i < 4) ? (ty * 4 + i) : (64 + ty * 4 + (i - 4));
        unsigned long long best = ~0ull;
#pragma unroll
        for (int j = 0; j < 8; ++j) {
            int nloc = (j < 4) ? (tx * 4 + j) : (64 + tx * 4 + (j - 4));
            // s = round(round(zsq + esq) - 2*dot)  (2*dot is exact)
            float tsum = __fadd_rn(zs[i], es[j]);
            float s    = __fsub_rn(tsum, __fmul_rn(2.0f, acc[i][j]));
            unsigned long long key =
                ((unsigned long long)f32_sortable(s) << 32)
                | (unsigned int)(nb * 128 + nloc);
            best = key < best ? key : best;
        }
        red[mloc][tx] = best;
    }
    __syncthreads();
    if (t < 128) {
        unsigned long long best = ~0ull;
#pragma unroll
        for (int x = 0; x < 16; ++x) {
            unsigned long long k = red[t][x];
            best = k < best ? k : best;
        }
        partials[(size_t)nb * N_PIX + mb * 128 + t] = best;
    }
}

// ---------------------------------------------------------------- kernel 5
// Combine the 64 candidate-tile partials per pixel -> final idx.
__global__ void reduce_idx_kernel(const unsigned long long* __restrict__ partials,
                                  int* __restrict__ idxbuf,
                                  float* __restrict__ idx_out) {
    int p = blockIdx.x * 256 + threadIdx.x;
    unsigned long long best = ~0ull;
    for (int nbv = 0; nbv < 64; ++nbv) {
        unsigned long long k = partials[(size_t)nbv * N_PIX + p];
        best = k < best ? k : best;
    }
    int k = (int)(unsigned int)(best & 0xffffffffu);
    idxbuf[p] = k;
    idx_out[p] = (float)k;   // harness reads flat buffer as float32
}

// ---------------------------------------------------------------- kernel 6
// Gather emb[idx] -> out (in [B,C,H,W] layout) + loss partial sums.
__global__ void gather_out_loss_kernel(const float* __restrict__ z,
                                       const float* __restrict__ emb,
                                       const int* __restrict__ idxbuf,
                                       float* __restrict__ out,
                                       double* __restrict__ lossAcc) {
    int bh = blockIdx.x;          // 0..511 = b*32 + h
    int b  = bh >> 5;
    int h  = bh & 31;
    int w  = threadIdx.x & 31;
    int cy = threadIdx.x >> 5;    // 0..7
    int n  = b * 1024 + h * 32 + w;
    int k  = idxbuf[n];
    const float* er = emb + (size_t)k * DDIM;
    float local = 0.f;
#pragma unroll 4
    for (int it = 0; it < 32; ++it) {
        int c = it * 8 + cy;
        float q = er[c];
        size_t off = ((size_t)b * 256 + c) * 1024 + h * 32 + w;
        float zv = z[off];
        out[off] = q;
        float d = q - zv;
        local += d * d;
    }
#pragma unroll
    for (int off = 32; off >= 1; off >>= 1) local += __shfl_down(local, off, 64);
    __shared__ float wsum[4];
    if ((threadIdx.x & 63) == 0) wsum[threadIdx.x >> 6] = local;
    __syncthreads();
    if (threadIdx.x == 0) {
        double s = (double)wsum[0] + (double)wsum[1]
                 + (double)wsum[2] + (double)wsum[3];
        atomicAdd(lossAcc, s);
    }
}

// ---------------------------------------------------------------- kernel 7
__global__ void finalize_loss_kernel(const double* __restrict__ lossAcc,
                                     float* __restrict__ loss_out) {
    // loss = q_latent + BETA*e_latent; both equal mean((q-z)^2) in value
    *loss_out = (float)(*lossAcc * (1.25 / 4194304.0));
}

// ----------------------------------------------------------------
extern "C" void kernel_launch(void* const* d_in, const int* in_sizes, int n_in,
                              void* d_out, int out_size, void* d_ws, size_t ws_size,
                              hipStream_t stream) {
    const float* z   = (const float*)d_in[0];   // [16,256,32,32]
    const float* emb = (const float*)d_in[1];   // [8192,256]
    float* out = (float*)d_out;                 // out | loss | idx
    char* ws = (char*)d_ws;

    float* A        = (float*)(ws + WS_A);
    unsigned long long* partials = (unsigned long long*)(ws + WS_PART);
    float* zsq      = (float*)(ws + WS_ZSQ);
    float* esq      = (float*)(ws + WS_ESQ);
    int*   idxbuf   = (int*)(ws + WS_IDX);
    double* lossAcc = (double*)(ws + WS_LOSS);

    zsq_kernel<<<64, 256, 0, stream>>>(z, zsq, lossAcc);
    esq_kernel<<<32, 256, 0, stream>>>(emb, esq);
    transpose_z_kernel<<<dim3(32, 8, 16), dim3(32, 8), 0, stream>>>(z, A);
    gemm_argmin_kernel<<<dim3(64, 128), 256, 0, stream>>>(A, emb, zsq, esq, partials);
    reduce_idx_kernel<<<64, 256, 0, stream>>>(partials, idxbuf, out + 4194305);
    gather_out_loss_kernel<<<512, 256, 0, stream>>>(z, emb, idxbuf, out, lossAcc);
    finalize_loss_kernel<<<1, 1, 0, stream>>>(lossAcc, out + 4194304);
}

// Round 3
// 304.203 us; speedup vs baseline: 2.8723x; 2.8723x over previous
//
#include <hip/hip_runtime.h>
#include <cstdint>
#include <cstddef>

#define N_PIX   16384
#define K_EMB   8192
#define DDIM    256

// ws layout (bytes) — total 25,329,672 (same footprint as the passing R2)
#define WS_ABF      0           // A bf16 pixel-major [16384][256]   8388608
#define WS_EBF      8388608     // E bf16 [8192][256]                4194304
#define WS_KEYS     12582912    // keys [16384][64*3] u32            12582912
#define WS_ZSQ      25165824    // 16384*4
#define WS_ESQ      25231360    // 8192*4
#define WS_IDX      25264128    // 16384*4
#define WS_LOSS     25329664    // 8

typedef short s16x8 __attribute__((ext_vector_type(8)));
typedef float f32x4 __attribute__((ext_vector_type(4)));

__device__ __forceinline__ unsigned int f32_sortable(float f) {
    unsigned int u = __float_as_uint(f);
    return (u & 0x80000000u) ? ~u : (u | 0x80000000u);
}

__device__ __forceinline__ unsigned short f2bf_rne(float x) {
    unsigned int u = __float_as_uint(x);
    unsigned int r = u + 0x7FFFu + ((u >> 16) & 1u);
    return (unsigned short)(r >> 16);
}

__device__ __forceinline__ void async16(const unsigned short* g, unsigned short* l) {
    __builtin_amdgcn_global_load_lds(
        (const __attribute__((address_space(1))) void*)g,
        (__attribute__((address_space(3))) void*)l, 16, 0, 0);
}

// ---------------------------------------------------------------- kernel 1
// zsq[p] = numpy-pairwise sum of z_p[c]^2 (exact np fp32 replication) + zero loss.
__global__ void zsq_kernel(const float* __restrict__ z,
                           float* __restrict__ zsq,
                           double* __restrict__ lossAcc) {
    int p  = blockIdx.x * 256 + threadIdx.x;
    int b  = p >> 10;
    int hw = p & 1023;
    const float* zp = z + (size_t)b * 262144 + hw;
    float r[16];
#pragma unroll
    for (int j = 0; j < 16; ++j) r[j] = 0.f;
#pragma unroll
    for (int c = 0; c < 256; ++c) {
        float x  = zp[(size_t)c * 1024];
        float sq = __fmul_rn(x, x);
        int slot = ((c >> 7) << 3) | (c & 7);
        r[slot] = __fadd_rn(r[slot], sq);
    }
    float h0 = __fadd_rn(
        __fadd_rn(__fadd_rn(r[0], r[1]), __fadd_rn(r[2], r[3])),
        __fadd_rn(__fadd_rn(r[4], r[5]), __fadd_rn(r[6], r[7])));
    float h1 = __fadd_rn(
        __fadd_rn(__fadd_rn(r[8], r[9]), __fadd_rn(r[10], r[11])),
        __fadd_rn(__fadd_rn(r[12], r[13]), __fadd_rn(r[14], r[15])));
    zsq[p] = __fadd_rn(h0, h1);
    if (p == 0) *lossAcc = 0.0;
}

// ---------------------------------------------------------------- kernel 2
// esq[k] exact (np pairwise) from fp32 emb.
__global__ void esq_kernel(const float* __restrict__ emb,
                           float* __restrict__ esq) {
    int k = blockIdx.x * 256 + threadIdx.x;
    const float* ep = emb + (size_t)k * DDIM;
    float r[16];
#pragma unroll
    for (int j = 0; j < 16; ++j) r[j] = 0.f;
#pragma unroll
    for (int c = 0; c < 256; ++c) {
        float x  = ep[c];
        float sq = __fmul_rn(x, x);
        int slot = ((c >> 7) << 3) | (c & 7);
        r[slot] = __fadd_rn(r[slot], sq);
    }
    float h0 = __fadd_rn(
        __fadd_rn(__fadd_rn(r[0], r[1]), __fadd_rn(r[2], r[3])),
        __fadd_rn(__fadd_rn(r[4], r[5]), __fadd_rn(r[6], r[7])));
    float h1 = __fadd_rn(
        __fadd_rn(__fadd_rn(r[8], r[9]), __fadd_rn(r[10], r[11])),
        __fadd_rn(__fadd_rn(r[12], r[13]), __fadd_rn(r[14], r[15])));
    esq[k] = __fadd_rn(h0, h1);
}

// ---------------------------------------------------------------- kernel 3
// z [B,C,H,W] fp32 -> Abf [p][c] bf16 (transpose + convert).
__global__ void pack_a_kernel(const float* __restrict__ z,
                              unsigned short* __restrict__ Abf) {
    __shared__ float tile[32][33];
    int pi = blockIdx.x, ci = blockIdx.y, b = blockIdx.z;
    int tx = threadIdx.x, ty = threadIdx.y;
#pragma unroll
    for (int i = ty; i < 32; i += 8)
        tile[i][tx] = z[((size_t)b * 256 + ci * 32 + i) * 1024 + pi * 32 + tx];
    __syncthreads();
#pragma unroll
    for (int i = ty; i < 32; i += 8)
        Abf[((size_t)b * 1024 + pi * 32 + i) * 256 + ci * 32 + tx] =
            f2bf_rne(tile[tx][i]);
}

// ---------------------------------------------------------------- kernel 4
__global__ void pack_e_kernel(const float* __restrict__ emb,
                              unsigned short* __restrict__ Ebf) {
    int t = blockIdx.x * 256 + threadIdx.x;      // 524288 threads, 4 elems each
    const float4 v = ((const float4*)emb)[t];
    ushort4 o;
    o.x = f2bf_rne(v.x); o.y = f2bf_rne(v.y);
    o.z = f2bf_rne(v.z); o.w = f2bf_rne(v.w);
    ((ushort4*)Ebf)[t] = o;
}

// ---------------------------------------------------------------- kernel 5
// bf16 MFMA GEMM: approx score shat = esq[n] - 2*dot_bf16(p,n); per
// (pixel, 128-candidate block) keep top-3 packed keys (score19<<13 | n).
__device__ __forceinline__ void merge3(unsigned &a0, unsigned &a1, unsigned &a2,
                                       unsigned b0, unsigned b1, unsigned b2) {
    unsigned m0 = min(a0, b0), M0 = max(a0, b0);
    unsigned m1 = min(a1, b1), M1 = max(a1, b1);
    unsigned m2 = min(a2, b2);
    unsigned c1 = min(M0, m1);
    unsigned c2 = min(max(M0, m1), min(M1, m2));
    a0 = m0; a1 = c1; a2 = c2;
}

__global__ __launch_bounds__(256) void mfma_score_kernel(
        const unsigned short* __restrict__ Abf,
        const unsigned short* __restrict__ Ebf,
        const float* __restrict__ esq,
        unsigned int* __restrict__ keys) {
    __shared__ __align__(16) unsigned short As[128 * 32];
    __shared__ __align__(16) unsigned short Bs[128 * 32];
    __shared__ unsigned int red[128][2][3];
    __shared__ float sEsq[128];

    const int nb = blockIdx.x;     // candidate block 0..63
    const int mb = blockIdx.y;     // pixel block 0..127
    const int t = threadIdx.x;
    const int w = t >> 6, lane = t & 63;
    const int wm = w >> 1, wn = w & 1;
    const int quad = lane >> 4, l16 = lane & 15;

    if (t < 128) sEsq[t] = esq[nb * 128 + t];

    // staging chunks: chunk c -> row=c>>2, slot=c&3 holds global sub=slot^swz(row)
    const int c0 = t, c1 = t + 256;
    const int r0 = c0 >> 2, s0 = (c0 & 3) ^ ((r0 ^ (r0 >> 2)) & 3);
    const int r1 = c1 >> 2, s1 = (c1 & 3) ^ ((r1 ^ (r1 >> 2)) & 3);

    const unsigned short* Ag = Abf + (size_t)(mb * 128) * 256;
    const unsigned short* Eg = Ebf + (size_t)(nb * 128) * 256;

    f32x4 acc[4][4];
#pragma unroll
    for (int i = 0; i < 4; ++i)
#pragma unroll
        for (int j = 0; j < 4; ++j)
#pragma unroll
            for (int r = 0; r < 4; ++r) acc[i][j][r] = 0.f;

    for (int k0 = 0; k0 < 256; k0 += 32) {
        __syncthreads();   // previous iteration's ds_reads complete
        async16(Ag + (size_t)r0 * 256 + k0 + s0 * 8, &As[c0 * 8]);
        async16(Ag + (size_t)r1 * 256 + k0 + s1 * 8, &As[c1 * 8]);
        async16(Eg + (size_t)r0 * 256 + k0 + s0 * 8, &Bs[c0 * 8]);
        async16(Eg + (size_t)r1 * 256 + k0 + s1 * 8, &Bs[c1 * 8]);
        __syncthreads();   // DMA complete (compiler drains vmcnt before barrier)

        s16x8 af[4], bfr[4];
#pragma unroll
        for (int fi = 0; fi < 4; ++fi) {
            int row  = wm * 64 + fi * 16 + l16;
            int slot = quad ^ ((row ^ (row >> 2)) & 3);
            af[fi] = *(const s16x8*)&As[row * 32 + slot * 8];
        }
#pragma unroll
        for (int fj = 0; fj < 4; ++fj) {
            int row  = wn * 64 + fj * 16 + l16;
            int slot = quad ^ ((row ^ (row >> 2)) & 3);
            bfr[fj] = *(const s16x8*)&Bs[row * 32 + slot * 8];
        }
#pragma unroll
        for (int fi = 0; fi < 4; ++fi)
#pragma unroll
            for (int fj = 0; fj < 4; ++fj)
                acc[fi][fj] = __builtin_amdgcn_mfma_f32_16x16x32_bf16(
                    af[fi], bfr[fj], acc[fi][fj], 0, 0, 0);
    }

    // epilogue: per-row top-3 over this block's 128 candidates
#pragma unroll
    for (int fi = 0; fi < 4; ++fi) {
#pragma unroll
        for (int r = 0; r < 4; ++r) {
            unsigned kk[4];
#pragma unroll
            for (int fj = 0; fj < 4; ++fj) {
                int nloc = wn * 64 + fj * 16 + l16;
                float sc = sEsq[nloc] - 2.0f * acc[fi][fj][r];
                sc = fminf(fmaxf(sc, -0.0624f), 0.0624f);
                unsigned u = (unsigned)((sc + 0.0625f) * 4194304.0f); // 2^22
                kk[fj] = (u << 13) | (unsigned)(nb * 128 + nloc);
            }
            // sort4 ascending, keep 3 smallest
            unsigned a = kk[0], b = kk[1], c = kk[2], d = kk[3], tmp;
#define CAS(x, y) { tmp = min(x, y); y = max(x, y); x = tmp; }
            CAS(a, b) CAS(c, d) CAS(a, c) CAS(b, d) CAS(b, c)
#undef CAS
            unsigned a0 = a, a1 = b, a2 = c;
#pragma unroll
            for (int m = 1; m < 16; m <<= 1) {
                unsigned b0 = __shfl_xor(a0, m, 64);
                unsigned b1 = __shfl_xor(a1, m, 64);
                unsigned b2 = __shfl_xor(a2, m, 64);
                merge3(a0, a1, a2, b0, b1, b2);
            }
            if (l16 == 0) {
                int row = wm * 64 + fi * 16 + quad * 4 + r;
                red[row][wn][0] = a0; red[row][wn][1] = a1; red[row][wn][2] = a2;
            }
        }
    }
    __syncthreads();
    if (t < 128) {
        unsigned a0 = red[t][0][0], a1 = red[t][0][1], a2 = red[t][0][2];
        merge3(a0, a1, a2, red[t][1][0], red[t][1][1], red[t][1][2]);
        size_t base = ((size_t)(mb * 128 + t)) * 192 + nb * 3;
        keys[base] = a0; keys[base + 1] = a1; keys[base + 2] = a2;
    }
}

// ---------------------------------------------------------------- kernel 6
// Per pixel: min over 192 keys, collect candidates within margin, exact
// rescore (fp64 dot -> np fp32 rounding), emit idx. One wave per pixel.
__global__ __launch_bounds__(256) void reduce_rescore_kernel(
        const unsigned int* __restrict__ keys,
        const float* __restrict__ z, const float* __restrict__ emb,
        const float* __restrict__ zsq, const float* __restrict__ esq,
        int* __restrict__ idxbuf, float* __restrict__ idx_out) {
    __shared__ int list[4][32];
    __shared__ int cnt[4];
    int w = threadIdx.x >> 6, lane = threadIdx.x & 63;
    int p = blockIdx.x * 4 + w;
    const unsigned int* kp = keys + (size_t)p * 192;

    unsigned u0 = kp[lane * 3 + 0];
    unsigned u1 = kp[lane * 3 + 1];
    unsigned u2 = kp[lane * 3 + 2];
    unsigned m = min(u0, min(u1, u2));
#pragma unroll
    for (int off = 32; off >= 1; off >>= 1) m = min(m, __shfl_down(m, off, 64));
    m = __shfl(m, 0, 64);
    unsigned thr_u = (m >> 13) + 1024;      // margin 1024 * 2^-22 = 2.44e-4

    if (lane == 0) cnt[w] = 0;
    __syncthreads();
    if ((u0 >> 13) <= thr_u) { int q = atomicAdd(&cnt[w], 1); if (q < 32) list[w][q] = (int)(u0 & 0x1FFFu); }
    if ((u1 >> 13) <= thr_u) { int q = atomicAdd(&cnt[w], 1); if (q < 32) list[w][q] = (int)(u1 & 0x1FFFu); }
    if ((u2 >> 13) <= thr_u) { int q = atomicAdd(&cnt[w], 1); if (q < 32) list[w][q] = (int)(u2 & 0x1FFFu); }
    __syncthreads();
    int n = min(cnt[w], 32);

    int b = p >> 10, hw = p & 1023;
    float zr0 = z[(size_t)b * 262144 + (size_t)(lane * 4 + 0) * 1024 + hw];
    float zr1 = z[(size_t)b * 262144 + (size_t)(lane * 4 + 1) * 1024 + hw];
    float zr2 = z[(size_t)b * 262144 + (size_t)(lane * 4 + 2) * 1024 + hw];
    float zr3 = z[(size_t)b * 262144 + (size_t)(lane * 4 + 3) * 1024 + hw];
    float zs = zsq[p];

    unsigned long long best = ~0ull;
    for (int i = 0; i < n; ++i) {
        int k = list[w][i];
        const float4 ev = *(const float4*)(emb + (size_t)k * DDIM + lane * 4);
        double d = (double)zr0 * ev.x + (double)zr1 * ev.y
                 + (double)zr2 * ev.z + (double)zr3 * ev.w;
#pragma unroll
        for (int off = 32; off >= 1; off >>= 1) d += __shfl_down(d, off, 64);
        d = __shfl(d, 0, 64);
        float df = (float)d;                           // np: fp32 matmul output
        float s  = __fsub_rn(__fadd_rn(zs, esq[k]), __fmul_rn(2.0f, df));
        unsigned long long key =
            ((unsigned long long)f32_sortable(s) << 32) | (unsigned)k;
        best = key < best ? key : best;
    }
    if (lane == 0) {
        int k = (int)(unsigned)(best & 0xffffffffu);
        idxbuf[p] = k;
        idx_out[p] = (float)k;
    }
}

// ---------------------------------------------------------------- kernel 7
__global__ void gather_out_loss_kernel(const float* __restrict__ z,
                                       const float* __restrict__ emb,
                                       const int* __restrict__ idxbuf,
                                       float* __restrict__ out,
                                       double* __restrict__ lossAcc) {
    int bh = blockIdx.x;
    int b  = bh >> 5;
    int h  = bh & 31;
    int w  = threadIdx.x & 31;
    int cy = threadIdx.x >> 5;
    int n  = b * 1024 + h * 32 + w;
    int k  = idxbuf[n];
    const float* er = emb + (size_t)k * DDIM;
    float local = 0.f;
#pragma unroll 4
    for (int it = 0; it < 32; ++it) {
        int c = it * 8 + cy;
        float q = er[c];
        size_t off = ((size_t)b * 256 + c) * 1024 + h * 32 + w;
        float zv = z[off];
        out[off] = q;
        float d = q - zv;
        local += d * d;
    }
#pragma unroll
    for (int off = 32; off >= 1; off >>= 1) local += __shfl_down(local, off, 64);
    __shared__ float wsum[4];
    if ((threadIdx.x & 63) == 0) wsum[threadIdx.x >> 6] = local;
    __syncthreads();
    if (threadIdx.x == 0) {
        double s = (double)wsum[0] + (double)wsum[1]
                 + (double)wsum[2] + (double)wsum[3];
        atomicAdd(lossAcc, s);
    }
}

// ---------------------------------------------------------------- kernel 8
__global__ void finalize_loss_kernel(const double* __restrict__ lossAcc,
                                     float* __restrict__ loss_out) {
    *loss_out = (float)(*lossAcc * (1.25 / 4194304.0));
}

// ----------------------------------------------------------------
extern "C" void kernel_launch(void* const* d_in, const int* in_sizes, int n_in,
                              void* d_out, int out_size, void* d_ws, size_t ws_size,
                              hipStream_t stream) {
    const float* z   = (const float*)d_in[0];
    const float* emb = (const float*)d_in[1];
    float* out = (float*)d_out;
    char* ws = (char*)d_ws;

    unsigned short* Abf = (unsigned short*)(ws + WS_ABF);
    unsigned short* Ebf = (unsigned short*)(ws + WS_EBF);
    unsigned int*  keys = (unsigned int*)(ws + WS_KEYS);
    float* zsq      = (float*)(ws + WS_ZSQ);
    float* esq      = (float*)(ws + WS_ESQ);
    int*   idxbuf   = (int*)(ws + WS_IDX);
    double* lossAcc = (double*)(ws + WS_LOSS);

    zsq_kernel<<<64, 256, 0, stream>>>(z, zsq, lossAcc);
    esq_kernel<<<32, 256, 0, stream>>>(emb, esq);
    pack_a_kernel<<<dim3(32, 8, 16), dim3(32, 8), 0, stream>>>(z, Abf);
    pack_e_kernel<<<2048, 256, 0, stream>>>(emb, Ebf);
    mfma_score_kernel<<<dim3(64, 128), 256, 0, stream>>>(Abf, Ebf, esq, keys);
    reduce_rescore_kernel<<<4096, 256, 0, stream>>>(keys, z, emb, zsq, esq,
                                                    idxbuf, out + 4194305);
    gather_out_loss_kernel<<<512, 256, 0, stream>>>(z, emb, idxbuf, out, lossAcc);
    finalize_loss_kernel<<<1, 1, 0, stream>>>(lossAcc, out + 4194304);
}

// Round 4
// 275.018 us; speedup vs baseline: 3.1772x; 1.1061x over previous
//
#include <hip/hip_runtime.h>
#include <cstdint>
#include <cstddef>

#define N_PIX   16384
#define K_EMB   8192
#define DDIM    256

// ws layout (bytes) — total 21,135,368 (< known-good 25,329,672)
#define WS_ABF      0           // A bf16 pixel-major [16384][256]   8388608
#define WS_EBF      8388608     // E bf16 [8192][256]                4194304
#define WS_KEYS     12582912    // keys [64][16384][2] u32           8388608
#define WS_ZSQ      20971520    // 16384*4
#define WS_ESQ      21037056    // 8192*4
#define WS_IDX      21069824    // 16384*4
#define WS_LOSS     21135360    // 8

typedef short s16x8 __attribute__((ext_vector_type(8)));
typedef float f32x4 __attribute__((ext_vector_type(4)));

__device__ __forceinline__ unsigned int f32_sortable(float f) {
    unsigned int u = __float_as_uint(f);
    return (u & 0x80000000u) ? ~u : (u | 0x80000000u);
}

__device__ __forceinline__ unsigned short f2bf_rne(float x) {
    unsigned int u = __float_as_uint(x);
    unsigned int r = u + 0x7FFFu + ((u >> 16) & 1u);
    return (unsigned short)(r >> 16);
}

__device__ __forceinline__ void async16(const unsigned short* g, unsigned short* l) {
    __builtin_amdgcn_global_load_lds(
        (const __attribute__((address_space(1))) void*)g,
        (__attribute__((address_space(3))) void*)l, 16, 0, 0);
}

// ---------------------------------------------------------------- kernel 1
// Fused: z [B,C,H,W] -> Abf [p][c] bf16 (transpose+convert) + zsq (exact np
// pairwise fp32) + zero lossAcc. 512 blocks x 32 pixels.
__global__ __launch_bounds__(256) void prep_a_kernel(
        const float* __restrict__ z,
        unsigned short* __restrict__ Abf,
        float* __restrict__ zsq,
        double* __restrict__ lossAcc) {
    __shared__ float tile[32][257];
    int blk = blockIdx.x;            // 0..511
    int b   = blk >> 5;
    int hw0 = (blk & 31) * 32;
    int t   = threadIdx.x;
    const float* zb = z + (size_t)b * 262144 + hw0;
    int px = t & 31;
    int cb = t >> 5;                 // 0..7
#pragma unroll
    for (int cc = 0; cc < 32; ++cc) {
        int c = cc * 8 + cb;
        tile[px][c] = zb[(size_t)c * 1024 + px];
    }
    __syncthreads();
    int p0 = b * 1024 + hw0;
    int wv = t >> 6, lane = t & 63;
#pragma unroll
    for (int iter = 0; iter < 8; ++iter) {
        int pl = iter * 4 + wv;
        ushort4 o;
        o.x = f2bf_rne(tile[pl][lane * 4 + 0]);
        o.y = f2bf_rne(tile[pl][lane * 4 + 1]);
        o.z = f2bf_rne(tile[pl][lane * 4 + 2]);
        o.w = f2bf_rne(tile[pl][lane * 4 + 3]);
        ((ushort4*)(Abf + (size_t)(p0 + pl) * 256))[lane] = o;
    }
    if (t < 32) {
        // numpy pairwise over 256: 2 halves x 8 interleaved slots
        float r[16];
#pragma unroll
        for (int j = 0; j < 16; ++j) r[j] = 0.f;
#pragma unroll
        for (int c = 0; c < 256; ++c) {
            float x  = tile[t][c];
            float sq = __fmul_rn(x, x);
            int slot = ((c >> 7) << 3) | (c & 7);
            r[slot] = __fadd_rn(r[slot], sq);
        }
        float h0 = __fadd_rn(
            __fadd_rn(__fadd_rn(r[0], r[1]), __fadd_rn(r[2], r[3])),
            __fadd_rn(__fadd_rn(r[4], r[5]), __fadd_rn(r[6], r[7])));
        float h1 = __fadd_rn(
            __fadd_rn(__fadd_rn(r[8], r[9]), __fadd_rn(r[10], r[11])),
            __fadd_rn(__fadd_rn(r[12], r[13]), __fadd_rn(r[14], r[15])));
        zsq[p0 + t] = __fadd_rn(h0, h1);
    }
    if (blk == 0 && t == 0) *lossAcc = 0.0;
}

// ---------------------------------------------------------------- kernel 2
// Fused: esq[k] (exact np pairwise) + Ebf bf16 conversion. One thread/row.
__global__ void prep_e_kernel(const float* __restrict__ emb,
                              unsigned short* __restrict__ Ebf,
                              float* __restrict__ esq) {
    int k = blockIdx.x * 256 + threadIdx.x;
    const float* ep = emb + (size_t)k * DDIM;
    ushort4* eb = (ushort4*)(Ebf + (size_t)k * DDIM);
    float r[16];
#pragma unroll
    for (int j = 0; j < 16; ++j) r[j] = 0.f;
#pragma unroll
    for (int c4 = 0; c4 < 64; ++c4) {
        float4 v = ((const float4*)ep)[c4];
        ushort4 o;
        o.x = f2bf_rne(v.x); o.y = f2bf_rne(v.y);
        o.z = f2bf_rne(v.z); o.w = f2bf_rne(v.w);
        eb[c4] = o;
        int c = c4 * 4;
        {
            int slot = ((c >> 7) << 3) | (c & 7);
            r[slot] = __fadd_rn(r[slot], __fmul_rn(v.x, v.x));
        }
        {
            int cc = c + 1; int slot = ((cc >> 7) << 3) | (cc & 7);
            r[slot] = __fadd_rn(r[slot], __fmul_rn(v.y, v.y));
        }
        {
            int cc = c + 2; int slot = ((cc >> 7) << 3) | (cc & 7);
            r[slot] = __fadd_rn(r[slot], __fmul_rn(v.z, v.z));
        }
        {
            int cc = c + 3; int slot = ((cc >> 7) << 3) | (cc & 7);
            r[slot] = __fadd_rn(r[slot], __fmul_rn(v.w, v.w));
        }
    }
    float h0 = __fadd_rn(
        __fadd_rn(__fadd_rn(r[0], r[1]), __fadd_rn(r[2], r[3])),
        __fadd_rn(__fadd_rn(r[4], r[5]), __fadd_rn(r[6], r[7])));
    float h1 = __fadd_rn(
        __fadd_rn(__fadd_rn(r[8], r[9]), __fadd_rn(r[10], r[11])),
        __fadd_rn(__fadd_rn(r[12], r[13]), __fadd_rn(r[14], r[15])));
    esq[k] = __fadd_rn(h0, h1);
}

// ---------------------------------------------------------------- kernel 3
// bf16 MFMA GEMM, double-buffered global_load_lds (1 barrier/iter):
// approx score shat = esq[n] - 2*dot_bf16(p,n); per (pixel, 128-cand block)
// keep top-2 packed keys (score19<<13 | n). keys block-major (coalesced).
__global__ __launch_bounds__(256) void mfma_score_kernel(
        const unsigned short* __restrict__ Abf,
        const unsigned short* __restrict__ Ebf,
        const float* __restrict__ esq,
        unsigned int* __restrict__ keys) {
    __shared__ __align__(16) unsigned short As[2][4096];  // 128 rows x 32 k
    __shared__ __align__(16) unsigned short Bs[2][4096];
    __shared__ unsigned int red[128][2][2];
    __shared__ float sEsq[128];

    const int nb = blockIdx.x;     // candidate block 0..63
    const int mb = blockIdx.y;     // pixel block 0..127
    const int t = threadIdx.x;
    const int w = t >> 6, lane = t & 63;
    const int wm = w >> 1, wn = w & 1;
    const int quad = lane >> 4, l16 = lane & 15;

    if (t < 128) sEsq[t] = esq[nb * 128 + t];

    // staging chunks: chunk c -> row=c>>2, slot=c&3 holds global sub=slot^swz(row)
    const int c0 = t, c1 = t + 256;
    const int r0 = c0 >> 2, s0 = (c0 & 3) ^ ((r0 ^ (r0 >> 2)) & 3);
    const int r1 = c1 >> 2, s1 = (c1 & 3) ^ ((r1 ^ (r1 >> 2)) & 3);

    const unsigned short* Ag = Abf + (size_t)(mb * 128) * 256;
    const unsigned short* Eg = Ebf + (size_t)(nb * 128) * 256;
    const unsigned short* a0g = Ag + (size_t)r0 * 256 + s0 * 8;
    const unsigned short* a1g = Ag + (size_t)r1 * 256 + s1 * 8;
    const unsigned short* e0g = Eg + (size_t)r0 * 256 + s0 * 8;
    const unsigned short* e1g = Eg + (size_t)r1 * 256 + s1 * 8;

    f32x4 acc[4][4];
#pragma unroll
    for (int i = 0; i < 4; ++i)
#pragma unroll
        for (int j = 0; j < 4; ++j)
#pragma unroll
            for (int r = 0; r < 4; ++r) acc[i][j][r] = 0.f;

    // prologue: DMA iter 0 into buffer 0
    async16(a0g, &As[0][c0 * 8]);
    async16(a1g, &As[0][c1 * 8]);
    async16(e0g, &Bs[0][c0 * 8]);
    async16(e1g, &Bs[0][c1 * 8]);

#pragma unroll
    for (int it = 0; it < 8; ++it) {
        const int cur = it & 1, nxt = cur ^ 1;
        __syncthreads();   // drains DMA for buf[cur]; prev reads of buf[nxt] done
        if (it < 7) {
            const int k0n = (it + 1) * 32;
            async16(a0g + k0n, &As[nxt][c0 * 8]);
            async16(a1g + k0n, &As[nxt][c1 * 8]);
            async16(e0g + k0n, &Bs[nxt][c0 * 8]);
            async16(e1g + k0n, &Bs[nxt][c1 * 8]);
        }
        s16x8 af[4], bfr[4];
#pragma unroll
        for (int fi = 0; fi < 4; ++fi) {
            int row  = wm * 64 + fi * 16 + l16;
            int slot = quad ^ ((row ^ (row >> 2)) & 3);
            af[fi] = *(const s16x8*)&As[cur][row * 32 + slot * 8];
        }
#pragma unroll
        for (int fj = 0; fj < 4; ++fj) {
            int row  = wn * 64 + fj * 16 + l16;
            int slot = quad ^ ((row ^ (row >> 2)) & 3);
            bfr[fj] = *(const s16x8*)&Bs[cur][row * 32 + slot * 8];
        }
#pragma unroll
        for (int fi = 0; fi < 4; ++fi)
#pragma unroll
            for (int fj = 0; fj < 4; ++fj)
                acc[fi][fj] = __builtin_amdgcn_mfma_f32_16x16x32_bf16(
                    af[fi], bfr[fj], acc[fi][fj], 0, 0, 0);
    }

    // epilogue: per-row top-2 over this block's 128 candidates
#pragma unroll
    for (int fi = 0; fi < 4; ++fi) {
#pragma unroll
        for (int r = 0; r < 4; ++r) {
            unsigned kk[4];
#pragma unroll
            for (int fj = 0; fj < 4; ++fj) {
                int nloc = wn * 64 + fj * 16 + l16;
                float sc = sEsq[nloc] - 2.0f * acc[fi][fj][r];
                sc = fminf(fmaxf(sc, -0.0624f), 0.0624f);
                unsigned u = (unsigned)((sc + 0.0625f) * 4194304.0f); // 2^22
                kk[fj] = (u << 13) | (unsigned)(nb * 128 + nloc);
            }
            unsigned lo0 = min(kk[0], kk[1]), hi0 = max(kk[0], kk[1]);
            unsigned lo1 = min(kk[2], kk[3]), hi1 = max(kk[2], kk[3]);
            unsigned a0 = min(lo0, lo1);
            unsigned a1 = min(max(lo0, lo1), min(hi0, hi1));
#pragma unroll
            for (int m = 1; m < 16; m <<= 1) {
                unsigned b0 = __shfl_xor(a0, m, 64);
                unsigned b1 = __shfl_xor(a1, m, 64);
                unsigned n0 = min(a0, b0);
                unsigned n1 = min(max(a0, b0), min(a1, b1));
                a0 = n0; a1 = n1;
            }
            if (l16 == 0) {
                int row = wm * 64 + fi * 16 + quad * 4 + r;
                red[row][wn][0] = a0;
                red[row][wn][1] = a1;
            }
        }
    }
    __syncthreads();
    if (t < 128) {
        unsigned a0 = red[t][0][0], a1 = red[t][0][1];
        unsigned b0 = red[t][1][0], b1 = red[t][1][1];
        unsigned n0 = min(a0, b0);
        unsigned n1 = min(max(a0, b0), min(a1, b1));
        size_t base = ((size_t)nb * N_PIX + (size_t)(mb * 128 + t)) * 2;
        keys[base]     = n0;   // coalesced: consecutive t -> consecutive 8B
        keys[base + 1] = n1;
    }
}

// ---------------------------------------------------------------- kernel 4
// Per pixel: min over 128 keys, collect candidates within margin, exact
// rescore (fp64 dot -> np fp32 rounding), emit idx. One wave per pixel.
__global__ __launch_bounds__(256) void reduce_rescore_kernel(
        const unsigned int* __restrict__ keys,
        const float* __restrict__ z, const float* __restrict__ emb,
        const float* __restrict__ zsq, const float* __restrict__ esq,
        int* __restrict__ idxbuf, float* __restrict__ idx_out) {
    __shared__ int list[4][32];
    __shared__ int cnt[4];
    int w = threadIdx.x >> 6, lane = threadIdx.x & 63;
    int p = blockIdx.x * 4 + w;

    // keys block-major: keys[nb][pixel][2]; lane = nb
    uint2 uv = *(const uint2*)(keys + ((size_t)lane * N_PIX + p) * 2);
    unsigned u0 = uv.x, u1 = uv.y;
    unsigned m = min(u0, u1);
#pragma unroll
    for (int off = 32; off >= 1; off >>= 1) m = min(m, __shfl_down(m, off, 64));
    m = __shfl(m, 0, 64);
    unsigned thr_u = (m >> 13) + 1024;      // margin 1024 * 2^-22 = 2.44e-4

    if (lane == 0) cnt[w] = 0;
    __syncthreads();
    if ((u0 >> 13) <= thr_u) { int q = atomicAdd(&cnt[w], 1); if (q < 32) list[w][q] = (int)(u0 & 0x1FFFu); }
    if ((u1 >> 13) <= thr_u) { int q = atomicAdd(&cnt[w], 1); if (q < 32) list[w][q] = (int)(u1 & 0x1FFFu); }
    __syncthreads();
    int n = min(cnt[w], 32);

    int b = p >> 10, hw = p & 1023;
    float zr0 = z[(size_t)b * 262144 + (size_t)(lane * 4 + 0) * 1024 + hw];
    float zr1 = z[(size_t)b * 262144 + (size_t)(lane * 4 + 1) * 1024 + hw];
    float zr2 = z[(size_t)b * 262144 + (size_t)(lane * 4 + 2) * 1024 + hw];
    float zr3 = z[(size_t)b * 262144 + (size_t)(lane * 4 + 3) * 1024 + hw];
    float zs = zsq[p];

    unsigned long long best = ~0ull;
    for (int i = 0; i < n; ++i) {
        int k = list[w][i];
        const float4 ev = *(const float4*)(emb + (size_t)k * DDIM + lane * 4);
        double d = (double)zr0 * ev.x + (double)zr1 * ev.y
                 + (double)zr2 * ev.z + (double)zr3 * ev.w;
#pragma unroll
        for (int off = 32; off >= 1; off >>= 1) d += __shfl_down(d, off, 64);
        d = __shfl(d, 0, 64);
        float df = (float)d;                           // np: fp32 matmul output
        float s  = __fsub_rn(__fadd_rn(zs, esq[k]), __fmul_rn(2.0f, df));
        unsigned long long key =
            ((unsigned long long)f32_sortable(s) << 32) | (unsigned)k;
        best = key < best ? key : best;
    }
    if (lane == 0) {
        int k = (int)(unsigned)(best & 0xffffffffu);
        idxbuf[p] = k;
        idx_out[p] = (float)k;
    }
}

// ---------------------------------------------------------------- kernel 5
__global__ void gather_out_loss_kernel(const float* __restrict__ z,
                                       const float* __restrict__ emb,
                                       const int* __restrict__ idxbuf,
                                       float* __restrict__ out,
                                       double* __restrict__ lossAcc) {
    int bh = blockIdx.x;
    int b  = bh >> 5;
    int h  = bh & 31;
    int w  = threadIdx.x & 31;
    int cy = threadIdx.x >> 5;
    int n  = b * 1024 + h * 32 + w;
    int k  = idxbuf[n];
    const float* er = emb + (size_t)k * DDIM;
    float local = 0.f;
#pragma unroll 4
    for (int it = 0; it < 32; ++it) {
        int c = it * 8 + cy;
        float q = er[c];
        size_t off = ((size_t)b * 256 + c) * 1024 + h * 32 + w;
        float zv = z[off];
        out[off] = q;
        float d = q - zv;
        local += d * d;
    }
#pragma unroll
    for (int off = 32; off >= 1; off >>= 1) local += __shfl_down(local, off, 64);
    __shared__ float wsum[4];
    if ((threadIdx.x & 63) == 0) wsum[threadIdx.x >> 6] = local;
    __syncthreads();
    if (threadIdx.x == 0) {
        double s = (double)wsum[0] + (double)wsum[1]
                 + (double)wsum[2] + (double)wsum[3];
        atomicAdd(lossAcc, s);
    }
}

// ---------------------------------------------------------------- kernel 6
__global__ void finalize_loss_kernel(const double* __restrict__ lossAcc,
                                     float* __restrict__ loss_out) {
    *loss_out = (float)(*lossAcc * (1.25 / 4194304.0));
}

// ----------------------------------------------------------------
extern "C" void kernel_launch(void* const* d_in, const int* in_sizes, int n_in,
                              void* d_out, int out_size, void* d_ws, size_t ws_size,
                              hipStream_t stream) {
    const float* z   = (const float*)d_in[0];
    const float* emb = (const float*)d_in[1];
    float* out = (float*)d_out;
    char* ws = (char*)d_ws;

    unsigned short* Abf = (unsigned short*)(ws + WS_ABF);
    unsigned short* Ebf = (unsigned short*)(ws + WS_EBF);
    unsigned int*  keys = (unsigned int*)(ws + WS_KEYS);
    float* zsq      = (float*)(ws + WS_ZSQ);
    float* esq      = (float*)(ws + WS_ESQ);
    int*   idxbuf   = (int*)(ws + WS_IDX);
    double* lossAcc = (double*)(ws + WS_LOSS);

    prep_a_kernel<<<512, 256, 0, stream>>>(z, Abf, zsq, lossAcc);
    prep_e_kernel<<<32, 256, 0, stream>>>(emb, Ebf, esq);
    mfma_score_kernel<<<dim3(64, 128), 256, 0, stream>>>(Abf, Ebf, esq, keys);
    reduce_rescore_kernel<<<4096, 256, 0, stream>>>(keys, z, emb, zsq, esq,
                                                    idxbuf, out + 4194305);
    gather_out_loss_kernel<<<512, 256, 0, stream>>>(z, emb, idxbuf, out, lossAcc);
    finalize_loss_kernel<<<1, 1, 0, stream>>>(lossAcc, out + 4194304);
}

// Round 5
// 224.151 us; speedup vs baseline: 3.8981x; 1.2269x over previous
//
#include <hip/hip_runtime.h>
#include <cstdint>
#include <cstddef>

#define N_PIX   16384
#define K_EMB   8192
#define DDIM    256

// ws layout (bytes) — total 21,069,832 (< known-good 25,329,672)
#define WS_ABF      0           // A bf16 pixel-major [16384][256]   8388608
#define WS_EBF      8388608     // E bf16 [8192][256]                4194304
#define WS_KEYS     12582912    // keys [16384][64] uint2            8388608
#define WS_ZSQ      20971520    // 16384*4
#define WS_ESQ      21037056    // 8192*4
#define WS_LOSS     21069824    // 8

typedef short s16x8 __attribute__((ext_vector_type(8)));
typedef float f32x4 __attribute__((ext_vector_type(4)));

__device__ __forceinline__ unsigned int f32_sortable(float f) {
    unsigned int u = __float_as_uint(f);
    return (u & 0x80000000u) ? ~u : (u | 0x80000000u);
}

__device__ __forceinline__ unsigned short f2bf_rne(float x) {
    unsigned int u = __float_as_uint(x);
    unsigned int r = u + 0x7FFFu + ((u >> 16) & 1u);
    return (unsigned short)(r >> 16);
}

__device__ __forceinline__ void async16(const unsigned short* g, unsigned short* l) {
    __builtin_amdgcn_global_load_lds(
        (const __attribute__((address_space(1))) void*)g,
        (__attribute__((address_space(3))) void*)l, 16, 0, 0);
}

// ---------------------------------------------------------------- kernel 1
// Fused prep: blocks 0..511 transpose+convert z -> Abf + zsq (np pairwise);
// blocks 512..543 convert emb -> Ebf + esq (np pairwise).
__global__ __launch_bounds__(256) void prep_kernel(
        const float* __restrict__ z, const float* __restrict__ emb,
        unsigned short* __restrict__ Abf, unsigned short* __restrict__ Ebf,
        float* __restrict__ zsq, float* __restrict__ esq,
        double* __restrict__ lossAcc) {
    __shared__ float tile[32][257];
    int blk = blockIdx.x;
    int t   = threadIdx.x;
    if (blk < 512) {
        int b   = blk >> 5;
        int hw0 = (blk & 31) * 32;
        const float* zb = z + (size_t)b * 262144 + hw0;
        int px = t & 31;
        int cb = t >> 5;
#pragma unroll
        for (int cc = 0; cc < 32; ++cc) {
            int c = cc * 8 + cb;
            tile[px][c] = zb[(size_t)c * 1024 + px];
        }
        __syncthreads();
        int p0 = b * 1024 + hw0;
        int wv = t >> 6, lane = t & 63;
#pragma unroll
        for (int iter = 0; iter < 8; ++iter) {
            int pl = iter * 4 + wv;
            ushort4 o;
            o.x = f2bf_rne(tile[pl][lane * 4 + 0]);
            o.y = f2bf_rne(tile[pl][lane * 4 + 1]);
            o.z = f2bf_rne(tile[pl][lane * 4 + 2]);
            o.w = f2bf_rne(tile[pl][lane * 4 + 3]);
            ((ushort4*)(Abf + (size_t)(p0 + pl) * 256))[lane] = o;
        }
        if (t < 32) {
            float r[16];
#pragma unroll
            for (int j = 0; j < 16; ++j) r[j] = 0.f;
#pragma unroll
            for (int c = 0; c < 256; ++c) {
                float x  = tile[t][c];
                float sq = __fmul_rn(x, x);
                int slot = ((c >> 7) << 3) | (c & 7);
                r[slot] = __fadd_rn(r[slot], sq);
            }
            float h0 = __fadd_rn(
                __fadd_rn(__fadd_rn(r[0], r[1]), __fadd_rn(r[2], r[3])),
                __fadd_rn(__fadd_rn(r[4], r[5]), __fadd_rn(r[6], r[7])));
            float h1 = __fadd_rn(
                __fadd_rn(__fadd_rn(r[8], r[9]), __fadd_rn(r[10], r[11])),
                __fadd_rn(__fadd_rn(r[12], r[13]), __fadd_rn(r[14], r[15])));
            zsq[p0 + t] = __fadd_rn(h0, h1);
        }
        if (blk == 0 && t == 0) *lossAcc = 0.0;
    } else {
        int k = (blk - 512) * 256 + t;
        const float* ep = emb + (size_t)k * DDIM;
        ushort4* eb = (ushort4*)(Ebf + (size_t)k * DDIM);
        float r[16];
#pragma unroll
        for (int j = 0; j < 16; ++j) r[j] = 0.f;
#pragma unroll
        for (int c4 = 0; c4 < 64; ++c4) {
            float4 v = ((const float4*)ep)[c4];
            ushort4 o;
            o.x = f2bf_rne(v.x); o.y = f2bf_rne(v.y);
            o.z = f2bf_rne(v.z); o.w = f2bf_rne(v.w);
            eb[c4] = o;
            int c = c4 * 4;
            { int slot = ((c >> 7) << 3) | (c & 7);
              r[slot] = __fadd_rn(r[slot], __fmul_rn(v.x, v.x)); }
            { int cc = c + 1; int slot = ((cc >> 7) << 3) | (cc & 7);
              r[slot] = __fadd_rn(r[slot], __fmul_rn(v.y, v.y)); }
            { int cc = c + 2; int slot = ((cc >> 7) << 3) | (cc & 7);
              r[slot] = __fadd_rn(r[slot], __fmul_rn(v.z, v.z)); }
            { int cc = c + 3; int slot = ((cc >> 7) << 3) | (cc & 7);
              r[slot] = __fadd_rn(r[slot], __fmul_rn(v.w, v.w)); }
        }
        float h0 = __fadd_rn(
            __fadd_rn(__fadd_rn(r[0], r[1]), __fadd_rn(r[2], r[3])),
            __fadd_rn(__fadd_rn(r[4], r[5]), __fadd_rn(r[6], r[7])));
        float h1 = __fadd_rn(
            __fadd_rn(__fadd_rn(r[8], r[9]), __fadd_rn(r[10], r[11])),
            __fadd_rn(__fadd_rn(r[12], r[13]), __fadd_rn(r[14], r[15])));
        esq[k] = __fadd_rn(h0, h1);
    }
}

// ---------------------------------------------------------------- kernel 2
// bf16 MFMA GEMM, dbuf DMA staging, LDS two-phase top-2 epilogue.
// Approx key: u = trunc((esq[n]+0.125 - 2*dot)*2^21) in [123k,402k) < 2^19;
// key = (u<<13)|n. Top-2 per (pixel, 128-cand block) -> keys[p][nb] (uint2).
__global__ __launch_bounds__(256) void mfma_score_kernel(
        const unsigned short* __restrict__ Abf,
        const unsigned short* __restrict__ Ebf,
        const float* __restrict__ esq,
        unsigned int* __restrict__ keys) {
    union SM {
        struct { unsigned short As[2][4096]; unsigned short Bs[2][4096]; } k;
        struct { uint2 ep[128][33]; } e;   // 33792 B, aliases staging
    };
    __shared__ SM sm;
    __shared__ float sEp[128];
    __shared__ uint2 pb[128][2];

    const int nb = blockIdx.x;     // candidate block 0..63
    const int mb = blockIdx.y;     // pixel block 0..127
    const int t = threadIdx.x;
    const int w = t >> 6, lane = t & 63;
    const int wm = w >> 1, wn = w & 1;
    const int quad = lane >> 4, l16 = lane & 15;

    if (t < 128)
        sEp[t] = (esq[nb * 128 + t] + 0.125f) * 2097152.0f;  // (esq+1/8)*2^21

    // staging chunks: chunk c -> row=c>>2, slot=c&3 holds global sub=slot^swz(row)
    const int c0 = t, c1 = t + 256;
    const int r0 = c0 >> 2, s0 = (c0 & 3) ^ ((r0 ^ (r0 >> 2)) & 3);
    const int r1 = c1 >> 2, s1 = (c1 & 3) ^ ((r1 ^ (r1 >> 2)) & 3);

    const unsigned short* Ag = Abf + (size_t)(mb * 128) * 256;
    const unsigned short* Eg = Ebf + (size_t)(nb * 128) * 256;
    const unsigned short* a0g = Ag + (size_t)r0 * 256 + s0 * 8;
    const unsigned short* a1g = Ag + (size_t)r1 * 256 + s1 * 8;
    const unsigned short* e0g = Eg + (size_t)r0 * 256 + s0 * 8;
    const unsigned short* e1g = Eg + (size_t)r1 * 256 + s1 * 8;

    f32x4 acc[4][4];
#pragma unroll
    for (int i = 0; i < 4; ++i)
#pragma unroll
        for (int j = 0; j < 4; ++j)
#pragma unroll
            for (int r = 0; r < 4; ++r) acc[i][j][r] = 0.f;

    // prologue: DMA iter 0 into buffer 0
    async16(a0g, &sm.k.As[0][c0 * 8]);
    async16(a1g, &sm.k.As[0][c1 * 8]);
    async16(e0g, &sm.k.Bs[0][c0 * 8]);
    async16(e1g, &sm.k.Bs[0][c1 * 8]);

#pragma unroll
    for (int it = 0; it < 8; ++it) {
        const int cur = it & 1, nxt = cur ^ 1;
        __syncthreads();
        if (it < 7) {
            const int k0n = (it + 1) * 32;
            async16(a0g + k0n, &sm.k.As[nxt][c0 * 8]);
            async16(a1g + k0n, &sm.k.As[nxt][c1 * 8]);
            async16(e0g + k0n, &sm.k.Bs[nxt][c0 * 8]);
            async16(e1g + k0n, &sm.k.Bs[nxt][c1 * 8]);
        }
        s16x8 af[4], bfr[4];
#pragma unroll
        for (int fi = 0; fi < 4; ++fi) {
            int row  = wm * 64 + fi * 16 + l16;
            int slot = quad ^ ((row ^ (row >> 2)) & 3);
            af[fi] = *(const s16x8*)&sm.k.As[cur][row * 32 + slot * 8];
        }
#pragma unroll
        for (int fj = 0; fj < 4; ++fj) {
            int row  = wn * 64 + fj * 16 + l16;
            int slot = quad ^ ((row ^ (row >> 2)) & 3);
            bfr[fj] = *(const s16x8*)&sm.k.Bs[cur][row * 32 + slot * 8];
        }
#pragma unroll
        for (int fi = 0; fi < 4; ++fi)
#pragma unroll
            for (int fj = 0; fj < 4; ++fj)
                acc[fi][fj] = __builtin_amdgcn_mfma_f32_16x16x32_bf16(
                    af[fi], bfr[fj], acc[fi][fj], 0, 0, 0);
    }

    __syncthreads();   // K-loop LDS reads done; safe to alias staging as ep[][]

    float epv[4];
    unsigned idxc[4];
#pragma unroll
    for (int fj = 0; fj < 4; ++fj) {
        int nloc = wn * 64 + fj * 16 + l16;
        epv[fj]  = sEp[nloc];
        idxc[fj] = (unsigned)(nb * 128 + nloc);
    }

    // phase A: per (fi,r) pack 4 keys, sort4 -> top2, one ds_write_b64
#pragma unroll
    for (int fi = 0; fi < 4; ++fi) {
#pragma unroll
        for (int r = 0; r < 4; ++r) {
            unsigned kk[4];
#pragma unroll
            for (int fj = 0; fj < 4; ++fj) {
                unsigned u = (unsigned)fmaf(acc[fi][fj][r], -4194304.0f, epv[fj]);
                kk[fj] = (u << 13) | idxc[fj];
            }
            unsigned lo0 = min(kk[0], kk[1]), hi0 = max(kk[0], kk[1]);
            unsigned lo1 = min(kk[2], kk[3]), hi1 = max(kk[2], kk[3]);
            unsigned a0 = min(lo0, lo1);
            unsigned a1 = min(max(lo0, lo1), min(hi0, hi1));
            int row = wm * 64 + fi * 16 + quad * 4 + r;
            sm.e.ep[row][wn * 16 + l16] = make_uint2(a0, a1);
        }
    }
    __syncthreads();

    // phase B1: 2 threads per row scan 16 entries each
    {
        int row = t >> 1, h0 = (t & 1) * 16;
        uint2 mv = sm.e.ep[row][h0];
#pragma unroll
        for (int i = 1; i < 16; ++i) {
            uint2 av = sm.e.ep[row][h0 + i];
            unsigned n0 = min(mv.x, av.x);
            unsigned n1 = min(max(mv.x, av.x), min(mv.y, av.y));
            mv.x = n0; mv.y = n1;
        }
        pb[row][t & 1] = mv;
    }
    __syncthreads();

    // phase B2: combine halves, write pixel-major keys
    if (t < 128) {
        uint2 x = pb[t][0], y = pb[t][1];
        unsigned n0 = min(x.x, y.x);
        unsigned n1 = min(max(x.x, y.x), min(x.y, y.y));
        ((uint2*)keys)[(size_t)(mb * 128 + t) * 64 + nb] = make_uint2(n0, n1);
    }
}

// ---------------------------------------------------------------- kernel 3
// Fused: per-(b,h) block of 32 pixels — LDS z-tile, keys min + margin
// candidates (ballot), exact rescore (fp64 dot -> np fp32), idx out,
// gather emb[idx] -> out, loss accumulation.
__global__ __launch_bounds__(256) void final_kernel(
        const unsigned int* __restrict__ keys,
        const float* __restrict__ z, const float* __restrict__ emb,
        const float* __restrict__ zsq, const float* __restrict__ esq,
        float* __restrict__ out, float* __restrict__ idx_out,
        double* __restrict__ lossAcc) {
    __shared__ float ztile[32][260];
    __shared__ int sidx[32];
    int blk = blockIdx.x;            // 0..511
    int b = blk >> 5, h = blk & 31;
    int t = threadIdx.x;
    int p0 = b * 1024 + h * 32;
    const float* zb = z + (size_t)b * 262144 + h * 32;
    {
        int px = t & 31, cb = t >> 5;
#pragma unroll
        for (int cc = 0; cc < 32; ++cc) {
            int c = cc * 8 + cb;
            ztile[px][c] = zb[(size_t)c * 1024 + px];
        }
    }
    __syncthreads();

    int wq = t >> 6, lane = t & 63;
    const uint2* kp = (const uint2*)keys;
#pragma unroll 1
    for (int i = 0; i < 8; ++i) {
        int px = wq * 8 + i;
        int p  = p0 + px;
        uint2 kv = kp[(size_t)p * 64 + lane];
        unsigned m = min(kv.x, kv.y);
#pragma unroll
        for (int off = 32; off >= 1; off >>= 1)
            m = min(m, (unsigned)__shfl_xor((int)m, off, 64));
        unsigned thr = (m >> 13) + 512;   // margin 512*2^-21 = 2.44e-4
        unsigned long long m0 = __ballot((kv.x >> 13) <= thr);
        unsigned long long m1 = __ballot((kv.y >> 13) <= thr);
        float4 zv = *(const float4*)&ztile[px][lane * 4];
        float zs = zsq[p];
        unsigned long long best = ~0ull;
        while (m0 | m1) {
            bool use0 = (m0 != 0);
            unsigned long long mm = use0 ? m0 : m1;
            int src = (int)__builtin_ctzll(mm);
            if (use0) m0 &= m0 - 1; else m1 &= m1 - 1;
            unsigned keyv = (unsigned)__shfl((int)(use0 ? kv.x : kv.y), src, 64);
            int k = (int)(keyv & 0x1FFFu);
            const float4 ev = *(const float4*)(emb + (size_t)k * DDIM + lane * 4);
            double d = (double)zv.x * ev.x + (double)zv.y * ev.y
                     + (double)zv.z * ev.z + (double)zv.w * ev.w;
#pragma unroll
            for (int off = 32; off >= 1; off >>= 1)
                d += __shfl_down(d, off, 64);
            d = __shfl(d, 0, 64);
            float df = (float)d;
            float s  = __fsub_rn(__fadd_rn(zs, esq[k]), __fmul_rn(2.0f, df));
            unsigned long long key =
                ((unsigned long long)f32_sortable(s) << 32) | (unsigned)k;
            best = key < best ? key : best;
        }
        if (lane == 0) {
            int k = (int)(unsigned)(best & 0xffffffffu);
            sidx[px] = k;
            idx_out[p] = (float)k;
        }
    }
    __syncthreads();

    // gather + loss (z from LDS)
    int wq2 = t & 31, cy = t >> 5;
    int kk = sidx[wq2];
    const float* er = emb + (size_t)kk * DDIM;
    float* ob = out + (size_t)b * 262144 + h * 32;
    float local = 0.f;
#pragma unroll 4
    for (int it = 0; it < 32; ++it) {
        int c = it * 8 + cy;
        float q = er[c];
        float d = q - ztile[wq2][c];
        ob[(size_t)c * 1024 + wq2] = q;
        local += d * d;
    }
#pragma unroll
    for (int off = 32; off >= 1; off >>= 1) local += __shfl_down(local, off, 64);
    __shared__ float wsum[4];
    if ((t & 63) == 0) wsum[t >> 6] = local;
    __syncthreads();
    if (t == 0) {
        double s = (double)wsum[0] + (double)wsum[1]
                 + (double)wsum[2] + (double)wsum[3];
        atomicAdd(lossAcc, s);
    }
}

// ---------------------------------------------------------------- kernel 4
__global__ void finalize_loss_kernel(const double* __restrict__ lossAcc,
                                     float* __restrict__ loss_out) {
    *loss_out = (float)(*lossAcc * (1.25 / 4194304.0));
}

// ----------------------------------------------------------------
extern "C" void kernel_launch(void* const* d_in, const int* in_sizes, int n_in,
                              void* d_out, int out_size, void* d_ws, size_t ws_size,
                              hipStream_t stream) {
    const float* z   = (const float*)d_in[0];
    const float* emb = (const float*)d_in[1];
    float* out = (float*)d_out;
    char* ws = (char*)d_ws;

    unsigned short* Abf = (unsigned short*)(ws + WS_ABF);
    unsigned short* Ebf = (unsigned short*)(ws + WS_EBF);
    unsigned int*  keys = (unsigned int*)(ws + WS_KEYS);
    float* zsq      = (float*)(ws + WS_ZSQ);
    float* esq      = (float*)(ws + WS_ESQ);
    double* lossAcc = (double*)(ws + WS_LOSS);

    prep_kernel<<<544, 256, 0, stream>>>(z, emb, Abf, Ebf, zsq, esq, lossAcc);
    mfma_score_kernel<<<dim3(64, 128), 256, 0, stream>>>(Abf, Ebf, esq, keys);
    final_kernel<<<512, 256, 0, stream>>>(keys, z, emb, zsq, esq,
                                          out, out + 4194305, lossAcc);
    finalize_loss_kernel<<<1, 1, 0, stream>>>(lossAcc, out + 4194304);
}